// Round 11
// baseline (281.180 us; speedup 1.0000x reference)
//
#include <hip/hip_runtime.h>
#include <cstdint>

typedef __attribute__((ext_vector_type(8))) short short8;
typedef __attribute__((ext_vector_type(4))) float floatx4;

__device__ __forceinline__ unsigned short f2bf(float f) {
  uint32_t u = __builtin_bit_cast(uint32_t, f);
  u += 0x7fffu + ((u >> 16) & 1u);   // RNE
  return (unsigned short)(u >> 16);
}
// pack bf16(lo)|bf16(hi)<<16, round-half-up: 2 adds + 1 v_perm
__device__ __forceinline__ uint32_t pkbf(float lo, float hi) {
  uint32_t a = __builtin_bit_cast(uint32_t, lo) + 0x8000u;
  uint32_t b = __builtin_bit_cast(uint32_t, hi) + 0x8000u;
  return __builtin_amdgcn_perm(b, a, 0x07060302);
}
// async global->LDS, 16B per lane (HW: wave-uniform LDS base + lane*16)
__device__ __forceinline__ void gll16(const void* g, void* l) {
  __builtin_amdgcn_global_load_lds(
      (const __attribute__((address_space(1))) unsigned int*)g,
      (__attribute__((address_space(3))) unsigned int*)l, 16, 0, 0);
}

// ---------------- kernel 1: build Wt LDS-image (fp32 -> bf16, swizzled) --------
// [bz(3)][kb(24)][row(192)][cs(4)] 16B chunks; chunk cs holds data k-chunk
// c = cs ^ ((row>>1)&3)  (XOR bank swizzle baked into the image).
__global__ void prep_w_kernel(const float* __restrict__ Wq,
                              const float* __restrict__ Wk,
                              const float* __restrict__ Wv,
                              unsigned short* __restrict__ Wt) {
  int id = blockIdx.x * 256 + threadIdx.x;      // 55296 chunks total
  int bz = id / 18432, rem = id - bz * 18432;
  int kb = rem / 768, s = rem - kb * 768;
  int row = s >> 2, cs = s & 3;                  // row = output col nn 0..191
  int c = cs ^ ((row >> 1) & 3);
  const float* W = (bz == 0) ? Wq : (bz == 1) ? Wk : Wv;
  int k0 = kb * 32 + c * 8;
  unsigned short v[8];
#pragma unroll
  for (int e = 0; e < 8; ++e) v[e] = f2bf(W[(size_t)(k0 + e) * 192 + row]);
  uint4 o;
  o.x = v[0] | ((uint32_t)v[1] << 16);
  o.y = v[2] | ((uint32_t)v[3] << 16);
  o.z = v[4] | ((uint32_t)v[5] << 16);
  o.w = v[6] | ((uint32_t)v[7] << 16);
  *(uint4*)(Wt + (size_t)id * 8) = o;
}

// ---------------- kernel 2: QKV projection + RoPE (v10 = v5 + XCD swizzle) ----
// v5 engine (best measured: 78us): 64x192 tile, reg-staged A, DMA'd B image,
// 3-buffer, counted vmcnt(7). NEW: 1-D grid with XCD sibling swizzle -- the 3
// bz-siblings of each m-tile get linear ids differing by multiples of 8, so
// they land on the SAME XCD and share the 393KB x-tile in that XCD's L2
// (dispatched within 16 id-slots of each other). Bijection: bid =
// ((3*(mt>>3)+bz)<<3)|(mt&7).
__global__ __launch_bounds__(256, 3) void proj_kernel(
    const float* __restrict__ x, const unsigned short* __restrict__ Wt,
    unsigned short* __restrict__ q_ws, unsigned short* __restrict__ k_ws,
    unsigned short* __restrict__ v_ws) {
  __shared__ __align__(16) unsigned short A_lds[3][64 * 32];    // 3 x 4KB
  __shared__ __align__(16) unsigned short B_lds[3][192 * 32];   // 3 x 12KB
  const int tid = threadIdx.x;
  const int w = tid >> 6, l = tid & 63, quad = l >> 4, ln = l & 15;
  const int wr = w & 1, wc = w >> 1;
  // XCD sibling swizzle: consecutive ids round-robin XCDs (id%8); siblings
  // (same mt, bz=0..2) share id%8 -> same XCD -> x-tile L2-shared.
  const int bid = blockIdx.x;              // 0..1535
  const int x0 = bid & 7, rr = bid >> 3;   // rr 0..191
  const int g = rr / 3, bz = rr - g * 3;   // g 0..63, bz 0..2
  const int mt = g * 8 + x0;               // 0..511
  const int m0 = mt * 64;

  const int arow = tid >> 2, ac = tid & 3;
  const int aslot = ((ac ^ ((arow >> 1) & 3)) << 4);
  const float* xp = x + (size_t)(m0 + arow) * 768 + ac * 8;
  const unsigned short* wimg = Wt + (size_t)bz * 18432 * 8;
  const int fq = ((quad ^ ((ln >> 1) & 3)) << 4);

  floatx4 acc[2][6];
#pragma unroll
  for (int mi = 0; mi < 2; ++mi)
#pragma unroll
    for (int nj = 0; nj < 6; ++nj) acc[mi][nj] = floatx4{0.f, 0.f, 0.f, 0.f};

  float4 ax0, ay0, ax1, ay1, ax2, ay2;  // 3 rotating A-prefetch reg sets

#define LOADA(S, K0)                               \
  do {                                             \
    ax##S = *(const float4*)(xp + (K0));           \
    ay##S = *(const float4*)(xp + (K0) + 4);       \
  } while (0)
#define STAGEA(S, AB)                                             \
  do {                                                            \
    uint4 ap;                                                     \
    ap.x = pkbf(ax##S.x, ax##S.y);                                \
    ap.y = pkbf(ax##S.z, ax##S.w);                                \
    ap.z = pkbf(ay##S.x, ay##S.y);                                \
    ap.w = pkbf(ay##S.z, ay##S.w);                                \
    *(uint4*)((char*)&A_lds[AB][0] + arow * 64 + aslot) = ap;     \
  } while (0)
#define DMAB(KB1, BB)                                             \
  do {                                                            \
    const unsigned short* src = wimg + (size_t)(KB1)*6144;        \
    char* dstb = (char*)&B_lds[BB][0];                            \
    gll16(src + tid * 8, dstb + tid * 16);                        \
    gll16(src + (256 + tid) * 8, dstb + (256 + tid) * 16);        \
    gll16(src + (512 + tid) * 8, dstb + (512 + tid) * 16);        \
  } while (0)
#define WAITBAR(N)                                                          \
  asm volatile("s_waitcnt vmcnt(" #N ") lgkmcnt(0)\n\ts_barrier" ::: "memory")
#define PCOMPUTE(C)                                                              \
  do {                                                                           \
    short8 af0 = *(const short8*)((const char*)&A_lds[C][0] +                    \
                                  (wr * 32 + ln) * 64 + fq);                     \
    short8 af1 = *(const short8*)((const char*)&A_lds[C][0] +                    \
                                  (wr * 32 + 16 + ln) * 64 + fq);                \
    _Pragma("unroll") for (int nj = 0; nj < 6; ++nj) {                           \
      short8 bf = *(const short8*)((const char*)&B_lds[C][0] +                   \
                                   (wc * 96 + nj * 16 + ln) * 64 + fq);          \
      acc[0][nj] = __builtin_amdgcn_mfma_f32_16x16x32_bf16(af0, bf, acc[0][nj],  \
                                                           0, 0, 0);             \
      acc[1][nj] = __builtin_amdgcn_mfma_f32_16x16x32_bf16(af1, bf, acc[1][nj],  \
                                                           0, 0, 0);             \
    }                                                                            \
  } while (0)
#define BODY(KB, C, P)            \
  do {                            \
    STAGEA(P, P);                 \
    DMAB((KB) + 1, P);            \
    LOADA(C, ((KB) + 3) * 32);    \
    WAITBAR(7);                   \
    PCOMPUTE(C);                  \
  } while (0)

  DMAB(0, 0);
  LOADA(0, 0);
  LOADA(1, 32);
  LOADA(2, 64);
  STAGEA(0, 0);

  BODY(0, 0, 1);
  for (int t = 1; t <= 16; t += 3) {
    BODY(t, 1, 2);
    BODY(t + 1, 2, 0);
    BODY(t + 2, 0, 1);
  }
  BODY(19, 1, 2);
  BODY(20, 2, 0);
  { STAGEA(1, 1); DMAB(22, 1); WAITBAR(5); PCOMPUTE(0); }
  { STAGEA(2, 2); DMAB(23, 2); WAITBAR(3); PCOMPUTE(1); }
  { WAITBAR(0); PCOMPUTE(2); }
#undef LOADA
#undef STAGEA
#undef DMAB
#undef WAITBAR
#undef PCOMPUTE
#undef BODY

  // epilogue. global col n = wc*96 + nj*16 + ln within 'which' bz.
  const float R_LG = 0.8304820237218406f;  // log2(10000)/16
#define ROPE2(V0, V1, TPOS)                                         \
  do {                                                              \
    float i0 = (float)(ln >> 1);                                    \
    float f0 = exp2f(-i0 * R_LG);                                   \
    float f1 = exp2f(-(i0 + 8.0f) * R_LG);                          \
    float s0, c0, s1, c1;                                            \
    sincosf((float)(TPOS)*f0, &s0, &c0);                            \
    sincosf((float)(TPOS)*f1, &s1, &c1);                            \
    float p0 = __shfl_xor(V0, 1), p1 = __shfl_xor(V1, 1);           \
    V0 = (ln & 1) ? (V0 * c0 + p0 * s0) : (V0 * c0 - p0 * s0);      \
    V1 = (ln & 1) ? (V1 * c1 + p1 * s1) : (V1 * c1 - p1 * s1);      \
  } while (0)

  if (bz < 2) {
    unsigned short* dst = (bz == 0) ? q_ws : k_ws;
    if (wc == 0) {
#pragma unroll
      for (int mi = 0; mi < 2; ++mi)
#pragma unroll
        for (int r = 0; r < 4; ++r) {
          int row_g = m0 + wr * 32 + mi * 16 + quad * 4 + r;
          int t_pos = row_g & 511;
          float v0 = acc[mi][0][r], v1 = acc[mi][1][r];
          ROPE2(v0, v1, t_pos);
          dst[(size_t)row_g * 192 + ln] = f2bf(v0);
          dst[(size_t)row_g * 192 + 16 + ln] = f2bf(v1);
#pragma unroll
          for (int nj = 2; nj < 6; ++nj)
            dst[(size_t)row_g * 192 + nj * 16 + ln] = f2bf(acc[mi][nj][r]);
        }
    } else {
#pragma unroll
      for (int mi = 0; mi < 2; ++mi)
#pragma unroll
        for (int r = 0; r < 4; ++r) {
          int row_g = m0 + wr * 32 + mi * 16 + quad * 4 + r;
#pragma unroll
          for (int nj = 0; nj < 6; ++nj)
            dst[(size_t)row_g * 192 + 96 + nj * 16 + ln] = f2bf(acc[mi][nj][r]);
        }
    }
  } else {
    const int dbase = wc * 96;
#pragma unroll
    for (int mi = 0; mi < 2; ++mi) {
      int rb = m0 + wr * 32 + mi * 16 + quad * 4;  // 4 consecutive rows, same batch
      int bb = rb >> 9, t = rb & 511;
#pragma unroll
      for (int nj = 0; nj < 6; ++nj) {
        ushort4 pv;
        pv.x = f2bf(acc[mi][nj][0]);
        pv.y = f2bf(acc[mi][nj][1]);
        pv.z = f2bf(acc[mi][nj][2]);
        pv.w = f2bf(acc[mi][nj][3]);
        *(ushort4*)&v_ws[((size_t)bb * 192 + dbase + nj * 16 + ln) * 512 + t] = pv;
      }
    }
  }
#undef ROPE2
}

// ---------------- kernel 3: causal flash attention (MFMA, KVBLK=64) -----------
// r6 structure (best measured; KVBLK=32 was +8us worse) + K/V register
// prefetch (T14): kt+1's 12 uint4 loads issued right after the stage barrier,
// HBM/L2 latency hidden under QK+softmax+PV. LDS 62.4KB -> 2 blocks/CU
// (needs VGPR <= ~256; no launch_bounds min so no spill-forcing cap).
__global__ __launch_bounds__(256) void attn_kernel(
    const unsigned short* __restrict__ q_ws, const unsigned short* __restrict__ k_ws,
    const unsigned short* __restrict__ v_ws, float* __restrict__ out) {
  __shared__ __align__(16) unsigned short K_lds[64 * 200];
  __shared__ __align__(16) unsigned short V_lds[192 * 72];   // V^T: [dim][key]
  __shared__ __align__(16) unsigned short P_lds[4][16 * 72]; // per-wave P
  const int tid = threadIdx.x;
  const int w = tid >> 6, l = tid & 63, quad = l >> 4, ln = l & 15;
  const int b = blockIdx.y;
  const int qt = (blockIdx.y < 32) ? blockIdx.x : 7 - blockIdx.x;
  const int q0 = qt * 64;

  // preload Q A-fragments
  short8 qf[6];
  {
    const unsigned short* qp =
        q_ws + (size_t)(b * 512 + q0 + w * 16 + ln) * 192 + quad * 8;
#pragma unroll
    for (int kk = 0; kk < 6; ++kk) qf[kk] = *(const short8*)(qp + kk * 32);
  }

  float m_i[4], l_i[4];
  floatx4 o[12];
#pragma unroll
  for (int r = 0; r < 4; ++r) { m_i[r] = -1e30f; l_i[r] = 0.f; }
#pragma unroll
  for (int nt = 0; nt < 12; ++nt) o[nt] = floatx4{0.f, 0.f, 0.f, 0.f};
  const float sm_scale = 0.07216878364870323f;  // 192^-0.5

  uint4 kpre0[6], vpre0[6], kpre1[6], vpre1[6];

#define AT_LOAD(KB, VB, K0)                                                        \
  do {                                                                             \
    _Pragma("unroll") for (int it = 0; it < 6; ++it) {                             \
      int idx = it * 256 + tid;                                                    \
      int row = idx / 24, c = idx - row * 24;                                      \
      (KB)[it] = *(const uint4*)(k_ws + (size_t)(b * 512 + (K0) + row) * 192 + c * 8); \
    }                                                                              \
    _Pragma("unroll") for (int it = 0; it < 6; ++it) {                             \
      int idx = it * 256 + tid;                                                    \
      int row = idx >> 3, c = idx & 7;                                             \
      (VB)[it] = *(const uint4*)(v_ws + (size_t)(b * 192 + row) * 512 + (K0) + c * 8); \
    }                                                                              \
  } while (0)
#define AT_STAGE(KB, VB)                                      \
  do {                                                        \
    _Pragma("unroll") for (int it = 0; it < 6; ++it) {        \
      int idx = it * 256 + tid;                               \
      int row = idx / 24, c = idx - row * 24;                 \
      *(uint4*)&K_lds[row * 200 + c * 8] = (KB)[it];          \
    }                                                         \
    _Pragma("unroll") for (int it = 0; it < 6; ++it) {        \
      int idx = it * 256 + tid;                               \
      int row = idx >> 3, c = idx & 7;                        \
      *(uint4*)&V_lds[row * 72 + c * 8] = (VB)[it];           \
    }                                                         \
  } while (0)

  AT_LOAD(kpre0, vpre0, 0);

  for (int kt = 0; kt <= qt; ++kt) {
    __syncthreads();  // previous iteration's LDS reads done before overwrite
    AT_STAGE(kpre0, vpre0);
    __syncthreads();
    if (kt < qt) AT_LOAD(kpre1, vpre1, (kt + 1) * 64);  // hides under compute

    // S = Q K^T (scaled)
    float s[4][4];
    __builtin_amdgcn_s_setprio(1);
#pragma unroll
    for (int nt = 0; nt < 4; ++nt) {
      floatx4 sa = floatx4{0.f, 0.f, 0.f, 0.f};
#pragma unroll
      for (int kk = 0; kk < 6; ++kk) {
        short8 kf = *(const short8*)&K_lds[(nt * 16 + ln) * 200 + kk * 32 + quad * 8];
        sa = __builtin_amdgcn_mfma_f32_16x16x32_bf16(qf[kk], kf, sa, 0, 0, 0);
      }
#pragma unroll
      for (int r = 0; r < 4; ++r) s[nt][r] = sa[r] * sm_scale;
    }
    __builtin_amdgcn_s_setprio(0);
    if (kt == qt) {  // diagonal tile mask (k0 == q0)
#pragma unroll
      for (int nt = 0; nt < 4; ++nt)
#pragma unroll
        for (int r = 0; r < 4; ++r)
          if (nt * 16 + ln > w * 16 + quad * 4 + r) s[nt][r] = -1e30f;
    }
    // online softmax (row = quad*4+r)
    float alpha[4];
#pragma unroll
    for (int r = 0; r < 4; ++r) {
      float mx = fmaxf(fmaxf(s[0][r], s[1][r]), fmaxf(s[2][r], s[3][r]));
      mx = fmaxf(mx, __shfl_xor(mx, 1));
      mx = fmaxf(mx, __shfl_xor(mx, 2));
      mx = fmaxf(mx, __shfl_xor(mx, 4));
      mx = fmaxf(mx, __shfl_xor(mx, 8));
      float mnew = fmaxf(m_i[r], mx);
      alpha[r] = __expf(m_i[r] - mnew);
      float sum = 0.f;
#pragma unroll
      for (int nt = 0; nt < 4; ++nt) {
        s[nt][r] = __expf(s[nt][r] - mnew);
        sum += s[nt][r];
      }
      sum += __shfl_xor(sum, 1);
      sum += __shfl_xor(sum, 2);
      sum += __shfl_xor(sum, 4);
      sum += __shfl_xor(sum, 8);
      l_i[r] = l_i[r] * alpha[r] + sum;
      m_i[r] = mnew;
    }
#pragma unroll
    for (int nt = 0; nt < 12; ++nt)
#pragma unroll
      for (int r = 0; r < 4; ++r) o[nt][r] *= alpha[r];

    // P: C/D layout -> A layout via per-wave LDS
#pragma unroll
    for (int nt = 0; nt < 4; ++nt)
#pragma unroll
      for (int r = 0; r < 4; ++r)
        P_lds[w][(quad * 4 + r) * 72 + nt * 16 + ln] = f2bf(s[nt][r]);
    __asm__ volatile("s_waitcnt lgkmcnt(0)" ::: "memory");  // wave-local write->read

    // O += P V
    __builtin_amdgcn_s_setprio(1);
#pragma unroll
    for (int ks = 0; ks < 2; ++ks) {
      short8 pf = *(const short8*)&P_lds[w][ln * 72 + ks * 32 + quad * 8];
#pragma unroll
      for (int nt = 0; nt < 12; ++nt) {
        short8 vf = *(const short8*)&V_lds[(nt * 16 + ln) * 72 + ks * 32 + quad * 8];
        o[nt] = __builtin_amdgcn_mfma_f32_16x16x32_bf16(pf, vf, o[nt], 0, 0, 0);
      }
    }
    __builtin_amdgcn_s_setprio(0);
    if (kt < qt) {
#pragma unroll
      for (int it = 0; it < 6; ++it) {
        kpre0[it] = kpre1[it];
        vpre0[it] = vpre1[it];
      }
    }
  }
#undef AT_LOAD
#undef AT_STAGE

  // epilogue: O/l -> fp32 out [b][t][dim]
#pragma unroll
  for (int r = 0; r < 4; ++r) {
    float inv = 1.0f / l_i[r];
    size_t rowoff = (size_t)(b * 512 + q0 + w * 16 + quad * 4 + r) * 192;
#pragma unroll
    for (int nt = 0; nt < 12; ++nt)
      out[rowoff + nt * 16 + ln] = o[nt][r] * inv;
  }
}

extern "C" void kernel_launch(void* const* d_in, const int* in_sizes, int n_in,
                              void* d_out, int out_size, void* d_ws, size_t ws_size,
                              hipStream_t stream) {
  const float* x = (const float*)d_in[0];
  const float* Wq = (const float*)d_in[1];
  const float* Wk = (const float*)d_in[2];
  const float* Wv = (const float*)d_in[3];
  float* out = (float*)d_out;

  char* ws = (char*)d_ws;
  const size_t QKV_BYTES = (size_t)64 * 512 * 192 * 2;  // 12,582,912
  unsigned short* q_ws = (unsigned short*)(ws);
  unsigned short* k_ws = (unsigned short*)(ws + QKV_BYTES);
  unsigned short* v_ws = (unsigned short*)(ws + 2 * QKV_BYTES);
  unsigned short* Wt = (unsigned short*)(ws + 3 * QKV_BYTES);  // 884,736 B image

  hipLaunchKernelGGL(prep_w_kernel, dim3(216), dim3(256), 0, stream, Wq, Wk, Wv, Wt);
  hipLaunchKernelGGL(proj_kernel, dim3(1536), dim3(256), 0, stream, x, Wt, q_ws, k_ws, v_ws);
  hipLaunchKernelGGL(attn_kernel, dim3(8, 64), dim3(256), 0, stream, q_ws, k_ws, v_ws, out);
}